// Round 1
// baseline (1575.373 us; speedup 1.0000x reference)
//
#include <hip/hip_runtime.h>
#include <hip/hip_bf16.h>

// Elman RNN: SEQ=2048, BATCH=64, IN=HID=256, fp32 in/out.
// Kernel 1: xp[b][t][n] (bf16, in d_ws) = x[t][b][:]·W_ih^T + b_ih + b_hh   (MFMA GEMM)
// Kernel 2: per-batch serial scan, one workgroup per batch, W_hh in registers,
//           h round-trips through LDS (C-layout -> A-layout), xp/out chunked
//           through LDS so per-step barriers have no outstanding vmem.

typedef short          bfrag8 __attribute__((ext_vector_type(8)));  // 8 bf16 (4 VGPRs)
typedef float          f4     __attribute__((ext_vector_type(4)));
typedef unsigned short us4    __attribute__((ext_vector_type(4)));
typedef unsigned int   ui4    __attribute__((ext_vector_type(4)));

#define HPAD 264   // 256 + 8 bf16 pad: keeps 16B alignment, breaks bank aliasing
#define CH   32    // time-steps per xp/out LDS chunk

static __device__ __forceinline__ unsigned short f2bf(float f) {
    union { float f; unsigned u; } v; v.f = f;
    unsigned r = v.u + 0x7FFFu + ((v.u >> 16) & 1u);   // RNE truncate
    return (unsigned short)(r >> 16);
}
static __device__ __forceinline__ float bf2f(unsigned short s) {
    union { unsigned u; float f; } v; v.u = ((unsigned)s) << 16;
    return v.f;
}

// ---------------------------------------------------------------- kernel 1
__global__ __launch_bounds__(256) void xp_gemm(
    const float* __restrict__ x, const float* __restrict__ Wih,
    const float* __restrict__ bih, const float* __restrict__ bhh,
    unsigned short* __restrict__ xp)
{
    __shared__ unsigned short xs[64 * HPAD];
    const int tid  = threadIdx.x;
    const int wave = tid >> 6;
    const int lane = tid & 63;
    const int l15  = lane & 15;
    const int quad = lane >> 4;
    const long r0  = (long)blockIdx.x * 64;      // rows are t*64+b

    // stage 64x256 fp32 -> bf16 LDS (coalesced dwordx4 reads)
    {
        const int rb = tid >> 6;          // 0..3
        const int cb = (tid & 63) * 4;    // 0..252
        #pragma unroll
        for (int it = 0; it < 16; ++it) {
            const int r = it * 4 + rb;
            const f4 v = *(const f4*)(x + (r0 + r) * 256 + cb);
            us4 o;
            o[0] = f2bf(v[0]); o[1] = f2bf(v[1]);
            o[2] = f2bf(v[2]); o[3] = f2bf(v[3]);
            *(us4*)(&xs[r * HPAD + cb]) = o;
        }
    }

    // B fragments from W_ih: B[k][n] = W_ih[n][k]; lane: n=l15(+tile), k=quad*8+j
    bfrag8 Bf[4][8];
    float  bs[4];
    #pragma unroll
    for (int nt = 0; nt < 4; ++nt) {
        const int n = wave * 64 + nt * 16 + l15;
        bs[nt] = bih[n] + bhh[n];
        #pragma unroll
        for (int kt = 0; kt < 8; ++kt) {
            const float* wp = Wih + n * 256 + kt * 32 + quad * 8;
            const f4 wa = *(const f4*)wp;
            const f4 wb = *(const f4*)(wp + 4);
            union { bfrag8 v; unsigned short s[8]; } u;
            #pragma unroll
            for (int j = 0; j < 4; ++j) { u.s[j] = f2bf(wa[j]); u.s[4 + j] = f2bf(wb[j]); }
            Bf[nt][kt] = u.v;
        }
    }

    __syncthreads();

    f4 acc[4][4];
    #pragma unroll
    for (int mt = 0; mt < 4; ++mt)
        #pragma unroll
        for (int nt = 0; nt < 4; ++nt)
            acc[mt][nt] = (f4){0.f, 0.f, 0.f, 0.f};

    #pragma unroll
    for (int kt = 0; kt < 8; ++kt) {
        bfrag8 Af[4];
        #pragma unroll
        for (int mt = 0; mt < 4; ++mt)
            Af[mt] = *(const bfrag8*)(&xs[(mt * 16 + l15) * HPAD + kt * 32 + quad * 8]);
        #pragma unroll
        for (int mt = 0; mt < 4; ++mt)
            #pragma unroll
            for (int nt = 0; nt < 4; ++nt)
                acc[mt][nt] = __builtin_amdgcn_mfma_f32_16x16x32_bf16(
                    Af[mt], Bf[nt][kt], acc[mt][nt], 0, 0, 0);
    }

    // store xp in [b][t][n] bf16 (the scan kernel's streaming layout)
    #pragma unroll
    for (int mt = 0; mt < 4; ++mt) {
        #pragma unroll
        for (int r = 0; r < 4; ++r) {
            const long g  = r0 + mt * 16 + quad * 4 + r;   // = t*64 + b
            const long t  = g >> 6;
            const long bb = g & 63;
            unsigned short* dst = xp + (bb * 2048 + t) * 256;
            #pragma unroll
            for (int nt = 0; nt < 4; ++nt)
                dst[wave * 64 + nt * 16 + l15] = f2bf(acc[mt][nt][r] + bs[nt]);
        }
    }
}

// ---------------------------------------------------------------- kernel 2
__global__ __launch_bounds__(256, 1) void rnn_scan(
    const unsigned short* __restrict__ xp, const float* __restrict__ Whh,
    float* __restrict__ out)
{
    __shared__ unsigned short hb[2][16 * HPAD];   // h in A-layout source, rows 1..15 = 0
    __shared__ unsigned short xl[2][CH * 256];    // xp chunks (bf16)
    __shared__ float          ost[CH * 256];      // output staging (fp32)

    const int tid  = threadIdx.x;
    const int wave = tid >> 6;
    const int lane = tid & 63;
    const int l15  = lane & 15;
    const int quad = lane >> 4;
    const int b    = blockIdx.x;

    for (int i = tid; i < 2 * 16 * HPAD; i += 256) (&hb[0][0])[i] = 0;

    // W_hh fragments: B[k][n] = W_hh[n][k], resident in VGPRs for the whole scan
    bfrag8 Bf[4][8];
    int nidx[4];
    #pragma unroll
    for (int nt = 0; nt < 4; ++nt) {
        const int n = wave * 64 + nt * 16 + l15;
        nidx[nt] = n;
        #pragma unroll
        for (int kt = 0; kt < 8; ++kt) {
            const float* wp = Whh + n * 256 + kt * 32 + quad * 8;
            const f4 wa = *(const f4*)wp;
            const f4 wb = *(const f4*)(wp + 4);
            union { bfrag8 v; unsigned short s[8]; } u;
            #pragma unroll
            for (int j = 0; j < 4; ++j) { u.s[j] = f2bf(wa[j]); u.s[4 + j] = f2bf(wb[j]); }
            Bf[nt][kt] = u.v;
        }
    }

    const unsigned short* xpb = xp + (long)b * 2048 * 256;

    // chunk 0 of xp -> LDS
    #pragma unroll
    for (int j = 0; j < 4; ++j)
        *(ui4*)(&xl[0][j * 2048 + tid * 8]) = *(const ui4*)(xpb + j * 2048 + tid * 8);
    __syncthreads();

    const int arow = l15 * HPAD + quad * 8;   // A-fragment base (bf16 units)

    for (int c = 0; c < 64; ++c) {
        const int t0 = c * CH;
        // prefetch next chunk into registers (drained at first step barrier; amortized)
        ui4 xq[4];
        {
            const int cc = (c < 63) ? (c + 1) : 63;
            const unsigned short* src = xpb + (long)cc * (CH * 256);
            #pragma unroll
            for (int j = 0; j < 4; ++j)
                xq[j] = *(const ui4*)(src + j * 2048 + tid * 8);
        }
        const unsigned short* xcur = &xl[c & 1][0];

        #pragma unroll 2
        for (int s = 0; s < CH; ++s) {
            // A fragments: h in rows of hb (rows 1..15 stay zero -> unused C rows = 0)
            bfrag8 Af[8];
            const unsigned short* hbp = &hb[s & 1][0];
            #pragma unroll
            for (int kt = 0; kt < 8; ++kt)
                Af[kt] = *(const bfrag8*)(hbp + arow + kt * 32);

            // C init = xp (only m=0 lane slots carry real data)
            f4 acc[4];
            #pragma unroll
            for (int nt = 0; nt < 4; ++nt) {
                const float xv = bf2f(xcur[s * 256 + nidx[nt]]);
                acc[nt] = (f4){0.f, 0.f, 0.f, 0.f};
                if (quad == 0) acc[nt][0] = xv;
            }

            #pragma unroll
            for (int kt = 0; kt < 8; ++kt)
                #pragma unroll
                for (int nt = 0; nt < 4; ++nt)
                    acc[nt] = __builtin_amdgcn_mfma_f32_16x16x32_bf16(
                        Af[kt], Bf[nt][kt], acc[nt], 0, 0, 0);

            if (quad == 0) {
                unsigned short* hw = &hb[(s & 1) ^ 1][0];
                #pragma unroll
                for (int nt = 0; nt < 4; ++nt) {
                    float z = acc[nt][0];
                    z = fminf(fmaxf(z, -12.f), 12.f);           // avoid inf/inf
                    const float e  = __expf(2.f * z);
                    const float hv = (e - 1.f) * __builtin_amdgcn_rcpf(e + 1.f);
                    ost[s * 256 + nidx[nt]] = hv;               // fp32 out staging
                    hw[nidx[nt]] = f2bf(hv);                    // bf16 h for next step
                }
            }
            __syncthreads();
        }

        // flush staged outputs (coalesced dwordx4) and install next xp chunk
        #pragma unroll
        for (int j = 0; j < 8; ++j) {
            const int f  = j * 1024 + tid * 4;
            const int ss = f >> 8;
            const int nn = f & 255;
            const f4 v = *(const f4*)(&ost[f]);
            *(f4*)(out + ((long)(t0 + ss) * 64 + b) * 256 + nn) = v;
        }
        {
            unsigned short* xdst = &xl[(c & 1) ^ 1][0];
            #pragma unroll
            for (int j = 0; j < 4; ++j)
                *(ui4*)(xdst + j * 2048 + tid * 8) = xq[j];
        }
        __syncthreads();
    }
}

extern "C" void kernel_launch(void* const* d_in, const int* in_sizes, int n_in,
                              void* d_out, int out_size, void* d_ws, size_t ws_size,
                              hipStream_t stream) {
    const float* x   = (const float*)d_in[0];
    const float* Wih = (const float*)d_in[1];
    const float* Whh = (const float*)d_in[2];
    const float* bih = (const float*)d_in[3];
    const float* bhh = (const float*)d_in[4];
    float* out = (float*)d_out;
    unsigned short* xpw = (unsigned short*)d_ws;   // 2048*64*256 bf16 = 64 MiB

    if (ws_size < (size_t)2048 * 64 * 256 * 2) return;  // fail visibly, don't corrupt

    xp_gemm<<<2048, 256, 0, stream>>>(x, Wih, bih, bhh, xpw);
    rnn_scan<<<64, 256, 0, stream>>>(xpw, Whh, out);
}

// Round 2
// 1203.819 us; speedup vs baseline: 1.3086x; 1.3086x over previous
//
#include <hip/hip_runtime.h>
#include <hip/hip_bf16.h>

// Elman RNN: SEQ=2048, BATCH=64, IN=HID=256, fp32 in/out.
// Kernel 1: xp[b][t][n] (bf16, in d_ws) = x[t]·W_ih^T + b_ih + b_hh (MFMA GEMM,
//           LDS-transposed coalesced 16B stores).
// Kernel 2: per-batch serial scan, one workgroup per batch, W_hh in registers.
//           h lives in ONE LDS row; A-operand rows {0,4,8,12} replicate it via
//           broadcast reads (zero-row for other m) -> all 4 quads get a full
//           result copy in reg0 -> epilogue = 1 tanh per lane. K-split dual
//           accumulators shorten the MFMA dep chain. xp streams in via
//           global_load_lds double-buffered 64-step chunks; outputs staged in
//           LDS and flushed coalesced per chunk.

typedef short          bfrag8 __attribute__((ext_vector_type(8)));  // 8 bf16 (4 VGPRs)
typedef float          f4     __attribute__((ext_vector_type(4)));
typedef unsigned short us4    __attribute__((ext_vector_type(4)));
typedef unsigned int   ui4    __attribute__((ext_vector_type(4)));

#define HPAD 264   // row pad (shorts): 16B-aligned rows
#define CH2  64    // time-steps per xp/out LDS chunk in the scan

static __device__ __forceinline__ unsigned short f2bf(float f) {
    union { float f; unsigned u; } v; v.f = f;
    unsigned r = v.u + 0x7FFFu + ((v.u >> 16) & 1u);   // RNE truncate
    return (unsigned short)(r >> 16);
}
static __device__ __forceinline__ float bf2f(unsigned short s) {
    union { unsigned u; float f; } v; v.u = ((unsigned)s) << 16;
    return v.f;
}
static __device__ __forceinline__ void gl2lds16(const unsigned short* g, unsigned short* l) {
    __builtin_amdgcn_global_load_lds(
        (const __attribute__((address_space(1))) void*)g,
        (__attribute__((address_space(3))) void*)l, 16, 0, 0);
}

// ---------------------------------------------------------------- kernel 1
__global__ __launch_bounds__(256) void xp_gemm(
    const float* __restrict__ x, const float* __restrict__ Wih,
    const float* __restrict__ bih, const float* __restrict__ bhh,
    unsigned short* __restrict__ xp)
{
    __shared__ unsigned short xs[64 * HPAD];   // A staging, then result staging
    const int tid  = threadIdx.x;
    const int wave = tid >> 6;
    const int lane = tid & 63;
    const int l15  = lane & 15;
    const int quad = lane >> 4;
    const int t    = blockIdx.x;               // one timestep per block
    const long r0  = (long)t * 64;             // rows of x viewed [T*B][I]

    // stage 64x256 fp32 -> bf16 LDS (coalesced dwordx4 reads)
    {
        const int rb = tid >> 6;
        const int cb = (tid & 63) * 4;
        #pragma unroll
        for (int it = 0; it < 16; ++it) {
            const int r = it * 4 + rb;
            const f4 v = *(const f4*)(x + (r0 + r) * 256 + cb);
            us4 o;
            o[0] = f2bf(v[0]); o[1] = f2bf(v[1]);
            o[2] = f2bf(v[2]); o[3] = f2bf(v[3]);
            *(us4*)(&xs[r * HPAD + cb]) = o;
        }
    }

    // B fragments from W_ih: B[k][n] = W_ih[n][k]; lane: n=l15(+tile), k=quad*8+j
    bfrag8 Bf[4][8];
    float  bs[4];
    #pragma unroll
    for (int nt = 0; nt < 4; ++nt) {
        const int n = wave * 64 + nt * 16 + l15;
        bs[nt] = bih[n] + bhh[n];
        #pragma unroll
        for (int kt = 0; kt < 8; ++kt) {
            const float* wp = Wih + n * 256 + kt * 32 + quad * 8;
            const f4 wa = *(const f4*)wp;
            const f4 wb = *(const f4*)(wp + 4);
            union { bfrag8 v; unsigned short s[8]; } u;
            #pragma unroll
            for (int j = 0; j < 4; ++j) { u.s[j] = f2bf(wa[j]); u.s[4 + j] = f2bf(wb[j]); }
            Bf[nt][kt] = u.v;
        }
    }

    __syncthreads();

    f4 acc[4][4];
    #pragma unroll
    for (int mt = 0; mt < 4; ++mt)
        #pragma unroll
        for (int nt = 0; nt < 4; ++nt)
            acc[mt][nt] = (f4){0.f, 0.f, 0.f, 0.f};

    #pragma unroll
    for (int kt = 0; kt < 8; ++kt) {
        bfrag8 Af[4];
        #pragma unroll
        for (int mt = 0; mt < 4; ++mt)
            Af[mt] = *(const bfrag8*)(&xs[(mt * 16 + l15) * HPAD + kt * 32 + quad * 8]);
        #pragma unroll
        for (int mt = 0; mt < 4; ++mt)
            #pragma unroll
            for (int nt = 0; nt < 4; ++nt)
                acc[mt][nt] = __builtin_amdgcn_mfma_f32_16x16x32_bf16(
                    Af[mt], Bf[nt][kt], acc[mt][nt], 0, 0, 0);
    }

    __syncthreads();   // all Af reads done; xs reusable

    // stage results (bf16, +bias) into xs as [b][n]
    #pragma unroll
    for (int mt = 0; mt < 4; ++mt)
        #pragma unroll
        for (int r = 0; r < 4; ++r) {
            const int bb = mt * 16 + quad * 4 + r;
            #pragma unroll
            for (int nt = 0; nt < 4; ++nt)
                xs[bb * HPAD + wave * 64 + nt * 16 + l15] = f2bf(acc[mt][nt][r] + bs[nt]);
        }

    __syncthreads();

    // coalesced 16B stores: xp[(b*2048 + t)*256 + n]
    #pragma unroll
    for (int i = 0; i < 8; ++i) {
        const int chunk = i * 256 + tid;
        const int bb  = chunk >> 5;
        const int seg = chunk & 31;
        const ui4 v = *(const ui4*)(&xs[bb * HPAD + seg * 8]);
        *(ui4*)(xp + ((long)bb * 2048 + t) * 256 + seg * 8) = v;
    }
}

// ---------------------------------------------------------------- kernel 2
__global__ __launch_bounds__(256, 1) void rnn_scan(
    const unsigned short* __restrict__ xp, const float* __restrict__ Whh,
    float* __restrict__ out)
{
    __shared__ unsigned short xl[2][CH2 * 256];   // xp chunks (bf16)  64 KB
    __shared__ float          ost[CH2 * 256];     // output staging     64 KB
    __shared__ unsigned short hb[2][2 * HPAD];    // row0 = h, row1 = zeros

    const int tid  = threadIdx.x;
    const int wave = tid >> 6;
    const int lane = tid & 63;
    const int l15  = lane & 15;
    const int quad = lane >> 4;
    const int b    = blockIdx.x;

    for (int i = tid; i < 2 * 2 * HPAD; i += 256) (&hb[0][0])[i] = 0;

    // W_hh fragments: B[k][n] = W_hh[n][k], resident in VGPRs for the whole scan
    bfrag8 Bf[4][8];
    #pragma unroll
    for (int nt = 0; nt < 4; ++nt) {
        const int n = wave * 64 + nt * 16 + l15;
        #pragma unroll
        for (int kt = 0; kt < 8; ++kt) {
            const float* wp = Whh + n * 256 + kt * 32 + quad * 8;
            const f4 wa = *(const f4*)wp;
            const f4 wb = *(const f4*)(wp + 4);
            union { bfrag8 v; unsigned short s[8]; } u;
            #pragma unroll
            for (int j = 0; j < 4; ++j) { u.s[j] = f2bf(wa[j]); u.s[4 + j] = f2bf(wb[j]); }
            Bf[nt][kt] = u.v;
        }
    }

    const unsigned short* xpb = xp + (long)b * 2048 * 256;

    // preload chunk 0 -> buf 0 (direct global->LDS DMA, lane-contiguous)
    #pragma unroll
    for (int i = 0; i < 8; ++i)
        gl2lds16(xpb + i * 2048 + tid * 8, &xl[0][i * 2048 + wave * 512]);

    // A rows {0,4,8,12} <- h row (broadcast); other rows <- zero row
    const int arow = (((l15 & 3) == 0) ? 0 : HPAD) + quad * 8;
    const int nsel = wave * 64 + quad * 16 + l15;   // this lane's output column
    int p = 0;

    for (int c = 0; c < 32; ++c) {
        // issue next chunk into the other buffer (drained at the barrier below)
        const int cn = (c < 31) ? c + 1 : 31;
        #pragma unroll
        for (int i = 0; i < 8; ++i)
            gl2lds16(xpb + (long)cn * (CH2 * 256) + i * 2048 + tid * 8,
                     &xl[(c + 1) & 1][i * 2048 + wave * 512]);

        __syncthreads();   // chunk data visible; ost safe to overwrite; stores drained

        const unsigned short* xcur = &xl[c & 1][0];

        #pragma unroll 2
        for (int s = 0; s < CH2; ++s) {
            const unsigned short* hbp = &hb[p][0];
            unsigned short*       hw  = &hb[p ^ 1][0];

            const float xv = bf2f(xcur[s * 256 + nsel]);  // issued early, used late

            bfrag8 Af[8];
            #pragma unroll
            for (int kt = 0; kt < 8; ++kt)
                Af[kt] = *(const bfrag8*)(hbp + arow + kt * 32);

            f4 accA[4], accB[4];
            #pragma unroll
            for (int nt = 0; nt < 4; ++nt) {
                accA[nt] = (f4){0.f, 0.f, 0.f, 0.f};
                accB[nt] = (f4){0.f, 0.f, 0.f, 0.f};
            }
            #pragma unroll
            for (int kt = 0; kt < 4; ++kt)
                #pragma unroll
                for (int nt = 0; nt < 4; ++nt) {
                    accA[nt] = __builtin_amdgcn_mfma_f32_16x16x32_bf16(
                        Af[kt],     Bf[nt][kt],     accA[nt], 0, 0, 0);
                    accB[nt] = __builtin_amdgcn_mfma_f32_16x16x32_bf16(
                        Af[kt + 4], Bf[nt][kt + 4], accB[nt], 0, 0, 0);
                }

            // every quad holds a full copy in reg0; this lane uses tile nt==quad
            const float za = (quad == 0) ? accA[0][0] : (quad == 1) ? accA[1][0]
                           : (quad == 2) ? accA[2][0] : accA[3][0];
            const float zb = (quad == 0) ? accB[0][0] : (quad == 1) ? accB[1][0]
                           : (quad == 2) ? accB[2][0] : accB[3][0];
            const float z  = za + zb + xv;

            // tanh(z) = 1 - 2/(exp2(z*2*log2e)+1); |z| <= ~20 so no clamps needed
            const float e2 = exp2f(z * 2.885390082f);
            const float hv = 1.f - 2.f * __builtin_amdgcn_rcpf(e2 + 1.f);

            ost[s * 256 + nsel] = hv;       // fp32 out staging
            hw[nsel] = f2bf(hv);            // bf16 h for next step

            p ^= 1;
            __syncthreads();
        }

        // flush staged outputs (coalesced dwordx4)
        const long t0 = (long)c * CH2;
        #pragma unroll
        for (int j = 0; j < 16; ++j) {
            const int f  = j * 1024 + tid * 4;
            const int ss = f >> 8;
            const int nn = f & 255;
            const f4 v = *(const f4*)(&ost[f]);
            *(f4*)(out + ((t0 + ss) * 64 + b) * 256 + nn) = v;
        }
    }
}

extern "C" void kernel_launch(void* const* d_in, const int* in_sizes, int n_in,
                              void* d_out, int out_size, void* d_ws, size_t ws_size,
                              hipStream_t stream) {
    const float* x   = (const float*)d_in[0];
    const float* Wih = (const float*)d_in[1];
    const float* Whh = (const float*)d_in[2];
    const float* bih = (const float*)d_in[3];
    const float* bhh = (const float*)d_in[4];
    float* out = (float*)d_out;
    unsigned short* xpw = (unsigned short*)d_ws;   // 2048*64*256 bf16 = 64 MiB

    if (ws_size < (size_t)2048 * 64 * 256 * 2) return;  // fail visibly, don't corrupt

    xp_gemm<<<2048, 256, 0, stream>>>(x, Wih, bih, bhh, xpw);
    rnn_scan<<<64, 256, 0, stream>>>(xpw, Whh, out);
}

// Round 3
// 1115.391 us; speedup vs baseline: 1.4124x; 1.0793x over previous
//
#include <hip/hip_runtime.h>
#include <hip/hip_bf16.h>

// Elman RNN: SEQ=2048, BATCH=64, IN=HID=256, fp32 in/out.
// Kernel 1: xp[b][t][n] (bf16, d_ws) = x[t]·W_ih^T + b_ih + b_hh.
//           256 blocks × 8 timesteps each: W_ih fragment load (scattered L2)
//           amortized 8x; per-t LDS transpose for coalesced 16B xp stores.
// Kernel 2: per-batch serial scan, one workgroup per batch, W_hh in VGPRs.
//           h lives in ONE contiguous 256-short LDS row; ALL A-rows read the
//           same slice (16-way broadcast, conflict-free). Garbage M-rows are
//           harmless (MFMA rows independent); every quad gets a replica of the
//           result in reg0 -> 1 tanh + 1 h-write per lane. Dual accumulators
//           (k-split) give 8 independent MFMA chains. xp streams via
//           global_load_lds in double-buffered 64-step chunks; outputs staged
//           in LDS, flushed coalesced per chunk.

typedef short          bfrag8 __attribute__((ext_vector_type(8)));  // 8 bf16 (4 VGPRs)
typedef float          f4     __attribute__((ext_vector_type(4)));
typedef unsigned short us4    __attribute__((ext_vector_type(4)));
typedef unsigned int   ui4    __attribute__((ext_vector_type(4)));

#define HPAD 264   // row pad (shorts) for the 64-row GEMM tiles
#define CH2  64    // time-steps per xp/out LDS chunk in the scan
#define TPB  8     // timesteps per block in xp_gemm

static __device__ __forceinline__ unsigned short f2bf(float f) {
    union { float f; unsigned u; } v; v.f = f;
    unsigned r = v.u + 0x7FFFu + ((v.u >> 16) & 1u);   // RNE truncate
    return (unsigned short)(r >> 16);
}
static __device__ __forceinline__ float bf2f(unsigned short s) {
    union { unsigned u; float f; } v; v.u = ((unsigned)s) << 16;
    return v.f;
}
static __device__ __forceinline__ void gl2lds16(const unsigned short* g, unsigned short* l) {
    __builtin_amdgcn_global_load_lds(
        (const __attribute__((address_space(1))) void*)g,
        (__attribute__((address_space(3))) void*)l, 16, 0, 0);
}

// ---------------------------------------------------------------- kernel 1
__global__ __launch_bounds__(256) void xp_gemm(
    const float* __restrict__ x, const float* __restrict__ Wih,
    const float* __restrict__ bih, const float* __restrict__ bhh,
    unsigned short* __restrict__ xp)
{
    __shared__ unsigned short xs[64 * HPAD];   // A staging (x tile, bf16)
    __shared__ unsigned short rs[64 * HPAD];   // result staging ([b][n] bf16)
    const int tid  = threadIdx.x;
    const int wave = tid >> 6;
    const int lane = tid & 63;
    const int l15  = lane & 15;
    const int quad = lane >> 4;
    const int t0   = blockIdx.x * TPB;

    // B fragments from W_ih (scattered L2 reads — done ONCE per block):
    // B[k][n] = W_ih[n][k]; lane: n=l15(+tile), k=quad*8+j
    bfrag8 Bf[4][8];
    float  bs[4];
    #pragma unroll
    for (int nt = 0; nt < 4; ++nt) {
        const int n = wave * 64 + nt * 16 + l15;
        bs[nt] = bih[n] + bhh[n];
        #pragma unroll
        for (int kt = 0; kt < 8; ++kt) {
            const float* wp = Wih + n * 256 + kt * 32 + quad * 8;
            const f4 wa = *(const f4*)wp;
            const f4 wb = *(const f4*)(wp + 4);
            union { bfrag8 v; unsigned short s[8]; } u;
            #pragma unroll
            for (int j = 0; j < 4; ++j) { u.s[j] = f2bf(wa[j]); u.s[4 + j] = f2bf(wb[j]); }
            Bf[nt][kt] = u.v;
        }
    }

    for (int tt = 0; tt < TPB; ++tt) {
        const int t = t0 + tt;

        // stage 64x256 fp32 -> bf16 LDS (coalesced dwordx4 reads)
        {
            const int rb = tid >> 6;
            const int cb = (tid & 63) * 4;
            #pragma unroll
            for (int it = 0; it < 16; ++it) {
                const int r = it * 4 + rb;
                const f4 v = *(const f4*)(x + ((long)t * 64 + r) * 256 + cb);
                us4 o;
                o[0] = f2bf(v[0]); o[1] = f2bf(v[1]);
                o[2] = f2bf(v[2]); o[3] = f2bf(v[3]);
                *(us4*)(&xs[r * HPAD + cb]) = o;
            }
        }
        __syncthreads();

        f4 acc[4][4];
        #pragma unroll
        for (int mt = 0; mt < 4; ++mt)
            #pragma unroll
            for (int nt = 0; nt < 4; ++nt)
                acc[mt][nt] = (f4){0.f, 0.f, 0.f, 0.f};

        #pragma unroll
        for (int kt = 0; kt < 8; ++kt) {
            bfrag8 Af[4];
            #pragma unroll
            for (int mt = 0; mt < 4; ++mt)
                Af[mt] = *(const bfrag8*)(&xs[(mt * 16 + l15) * HPAD + kt * 32 + quad * 8]);
            #pragma unroll
            for (int mt = 0; mt < 4; ++mt)
                #pragma unroll
                for (int nt = 0; nt < 4; ++nt)
                    acc[mt][nt] = __builtin_amdgcn_mfma_f32_16x16x32_bf16(
                        Af[mt], Bf[nt][kt], acc[mt][nt], 0, 0, 0);
        }
        __syncthreads();   // all xs reads done

        // stage results (bf16, +bias) into rs as [b][n]
        #pragma unroll
        for (int mt = 0; mt < 4; ++mt)
            #pragma unroll
            for (int r = 0; r < 4; ++r) {
                const int bb = mt * 16 + quad * 4 + r;
                #pragma unroll
                for (int nt = 0; nt < 4; ++nt)
                    rs[bb * HPAD + wave * 64 + nt * 16 + l15] = f2bf(acc[mt][nt][r] + bs[nt]);
            }
        __syncthreads();

        // coalesced 16B stores: xp[(b*2048 + t)*256 + n]
        #pragma unroll
        for (int i = 0; i < 8; ++i) {
            const int chunk = i * 256 + tid;
            const int bb  = chunk >> 5;
            const int seg = chunk & 31;
            const ui4 v = *(const ui4*)(&rs[bb * HPAD + seg * 8]);
            *(ui4*)(xp + ((long)bb * 2048 + t) * 256 + seg * 8) = v;
        }
        __syncthreads();   // store-reads of rs done before next iter's rs write
    }
}

// ---------------------------------------------------------------- kernel 2
__global__ __launch_bounds__(256, 1) void rnn_scan(
    const unsigned short* __restrict__ xp, const float* __restrict__ Whh,
    float* __restrict__ out)
{
    __shared__ unsigned short xl[2][CH2 * 256];       // xp chunks (bf16)  64 KB
    __shared__ float          ost[CH2 * 256];         // output staging     64 KB
    __shared__ __align__(16) unsigned short hrow[2][256];  // ping-pong h (bf16)

    const int tid  = threadIdx.x;
    const int wave = tid >> 6;
    const int lane = tid & 63;
    const int l15  = lane & 15;
    const int quad = lane >> 4;
    const int b    = blockIdx.x;

    if (tid < 32) ((ui4*)&hrow[0][0])[tid] = (ui4){0u, 0u, 0u, 0u};  // h0 = 0

    // W_hh fragments: B[k][n] = W_hh[n][k], resident in VGPRs for the whole scan
    bfrag8 Bf[4][8];
    #pragma unroll
    for (int nt = 0; nt < 4; ++nt) {
        const int n = wave * 64 + nt * 16 + l15;
        #pragma unroll
        for (int kt = 0; kt < 8; ++kt) {
            const float* wp = Whh + n * 256 + kt * 32 + quad * 8;
            const f4 wa = *(const f4*)wp;
            const f4 wb = *(const f4*)(wp + 4);
            union { bfrag8 v; unsigned short s[8]; } u;
            #pragma unroll
            for (int j = 0; j < 4; ++j) { u.s[j] = f2bf(wa[j]); u.s[4 + j] = f2bf(wb[j]); }
            Bf[nt][kt] = u.v;
        }
    }

    const unsigned short* xpb = xp + (long)b * 2048 * 256;

    // preload chunk 0 -> buf 0 (direct global->LDS DMA, lane-contiguous)
    #pragma unroll
    for (int i = 0; i < 8; ++i)
        gl2lds16(xpb + i * 2048 + tid * 8, &xl[0][i * 2048 + wave * 512]);

    const int abase = quad * 8;                       // A slice: k = quad*8 + j
    const int nsel  = wave * 64 + quad * 16 + l15;    // this lane's output column
    int p = 0;

    for (int c = 0; c < 32; ++c) {
        // issue next chunk into the other buffer (drained at the barrier below)
        const int cn = (c < 31) ? c + 1 : 31;
        #pragma unroll
        for (int i = 0; i < 8; ++i)
            gl2lds16(xpb + (long)cn * (CH2 * 256) + i * 2048 + tid * 8,
                     &xl[(c + 1) & 1][i * 2048 + wave * 512]);

        __syncthreads();   // chunk visible; ost safe to overwrite; stores drained

        const unsigned short* xcur = &xl[c & 1][0];

        #pragma unroll 2
        for (int s = 0; s < CH2; ++s) {
            const float xv = bf2f(xcur[s * 256 + nsel]);  // issued early, used late

            // A fragments: pure broadcast of h (all M-rows identical -> all
            // D-rows are valid replicas; no zero rows needed)
            bfrag8 Af[8];
            const unsigned short* hbp = &hrow[p][0];
            #pragma unroll
            for (int kt = 0; kt < 8; ++kt)
                Af[kt] = *(const bfrag8*)(hbp + abase + kt * 32);

            f4 accA[4], accB[4];
            #pragma unroll
            for (int nt = 0; nt < 4; ++nt) {
                accA[nt] = (f4){0.f, 0.f, 0.f, 0.f};
                accB[nt] = (f4){0.f, 0.f, 0.f, 0.f};
            }
            #pragma unroll
            for (int kt = 0; kt < 4; ++kt)
                #pragma unroll
                for (int nt = 0; nt < 4; ++nt) {
                    accA[nt] = __builtin_amdgcn_mfma_f32_16x16x32_bf16(
                        Af[kt],     Bf[nt][kt],     accA[nt], 0, 0, 0);
                    accB[nt] = __builtin_amdgcn_mfma_f32_16x16x32_bf16(
                        Af[kt + 4], Bf[nt][kt + 4], accB[nt], 0, 0, 0);
                }

            // every quad holds a full replica in reg0; lane uses tile nt==quad
            const float za = (quad == 0) ? accA[0][0] : (quad == 1) ? accA[1][0]
                           : (quad == 2) ? accA[2][0] : accA[3][0];
            const float zb = (quad == 0) ? accB[0][0] : (quad == 1) ? accB[1][0]
                           : (quad == 2) ? accB[2][0] : accB[3][0];
            const float z  = za + zb + xv;

            // tanh(z) = 1 - 2/(exp2(z*2*log2e)+1); |z| small enough, no clamps
            const float e2 = exp2f(z * 2.885390082f);
            const float hv = 1.f - 2.f * __builtin_amdgcn_rcpf(e2 + 1.f);

            hrow[p ^ 1][nsel] = f2bf(hv);   // h for next step (critical path)
            ost[s * 256 + nsel] = hv;       // fp32 out staging

            p ^= 1;
            __syncthreads();
        }

        // flush staged outputs (coalesced dwordx4)
        const long t0 = (long)c * CH2;
        #pragma unroll
        for (int j = 0; j < 16; ++j) {
            const int f  = j * 1024 + tid * 4;
            const int ss = f >> 8;
            const int nn = f & 255;
            const f4 v = *(const f4*)(&ost[f]);
            *(f4*)(out + ((t0 + ss) * 64 + b) * 256 + nn) = v;
        }
    }
}

extern "C" void kernel_launch(void* const* d_in, const int* in_sizes, int n_in,
                              void* d_out, int out_size, void* d_ws, size_t ws_size,
                              hipStream_t stream) {
    const float* x   = (const float*)d_in[0];
    const float* Wih = (const float*)d_in[1];
    const float* Whh = (const float*)d_in[2];
    const float* bih = (const float*)d_in[3];
    const float* bhh = (const float*)d_in[4];
    float* out = (float*)d_out;
    unsigned short* xpw = (unsigned short*)d_ws;   // 2048*64*256 bf16 = 64 MiB

    if (ws_size < (size_t)2048 * 64 * 256 * 2) return;  // fail visibly, don't corrupt

    xp_gemm<<<2048 / TPB, 256, 0, stream>>>(x, Wih, bih, bhh, xpw);
    rnn_scan<<<64, 256, 0, stream>>>(xpw, Whh, out);
}